// Round 5
// baseline (622.961 us; speedup 1.0000x reference)
//
#include <hip/hip_runtime.h>
#include <hip/hip_bf16.h>
#include <math.h>

#define BB 64
#define DD 256
#define TT 24
#define NR 289

typedef float f32x4 __attribute__((ext_vector_type(4)));
typedef short bf16x8 __attribute__((ext_vector_type(8)));

// ws layout (bytes)
#define ET_OFF   0ul                     // eT  [64][32][256] bf16 (t>=24 zero)   1,048,576
#define VT_OFF   1048576ul               // vT  [64][304][256] bf16 (n>=289 zero) 9,961,472
#define VBF_OFF  11010048ul              // vbf [64][256][320] bf16 (n>=289 zero) 10,485,760
#define SMAT_OFF 21495808ul              // Smat [4096] f32

// ---- convert e -> eT[i][t][d] bf16, rows t>=24 zeroed
__global__ void conv_e_kernel(const float* __restrict__ e, __hip_bfloat16* __restrict__ eT) {
    int i = blockIdx.x, d = threadIdx.x;
    const float* src = e + ((size_t)i * DD + d) * TT;
    __hip_bfloat16* dst = eT + (size_t)i * 32 * DD + d;
    #pragma unroll
    for (int t = 0; t < 32; ++t) {
        float vv = (t < TT) ? src[t] : 0.f;
        dst[(size_t)t * DD] = __float2bfloat16(vv);
    }
}

// ---- convert v -> vT[j][n][d] and vbf[j][d][n] (both bf16, padded with zeros)
__global__ __launch_bounds__(256) void conv_v_kernel(const float* __restrict__ v,
                                                     __hip_bfloat16* __restrict__ vT,
                                                     __hip_bfloat16* __restrict__ vbf) {
    __shared__ float ld[32][305];   // pitch 305: coprime with 32 -> conflict-free col reads
    int j = blockIdx.x >> 3;
    int dbase = (blockIdx.x & 7) * 32;
    int tid = threadIdx.x;
    const float* vj = v + (size_t)j * DD * NR;
    for (int r = 0; r < 32; ++r) {
        const float* row = vj + (size_t)(dbase + r) * NR;
        ld[r][tid] = row[tid];
        if (tid < 48) {
            int n = 256 + tid;
            ld[r][n] = (n < NR) ? row[n] : 0.f;
        }
    }
    __syncthreads();
    { // vT[j][n][dbase+d], coalesced 32-lane writes
        int d = tid & 31, ng = tid >> 5;
        __hip_bfloat16* base = vT + (size_t)j * 304 * DD + dbase + d;
        for (int n = ng; n < 304; n += 8)
            base[(size_t)n * DD] = __float2bfloat16(ld[d][n]);
    }
    { // vbf[j][dbase+r][n], coalesced
        __hip_bfloat16* base = vbf + ((size_t)j * DD + dbase) * 320;
        for (int idx = tid; idx < 32 * 320; idx += 256) {
            int r = idx / 320, n = idx - r * 320;
            float vv = (n < NR) ? ld[r][n] : 0.f;
            base[(size_t)r * 320 + n] = __float2bfloat16(vv);
        }
    }
}

// ---- one block (512 thr, 8 waves) per (i,j) pair; Smat[j*64+i] = S[i][j]
// Scores never round-trip through LDS: GEMM1 accs stay in registers through
// both softmaxes; only alpha (GEMM2's A operand) is written to LDS (swizzled).
// LDS = 20480 (alpha) + 2048 (per-wave softmax-n partials) = 22528 B.
__global__ __launch_bounds__(512, 6) void pair_kernel(const float* __restrict__ e,
                                                      const __hip_bfloat16* __restrict__ eT,
                                                      const __hip_bfloat16* __restrict__ vT,
                                                      const __hip_bfloat16* __restrict__ vbf,
                                                      float* __restrict__ Smat) {
    __shared__ __align__(16) __hip_bfloat16 alpha[32 * 320];  // XOR-swizzled rows
    __shared__ __align__(16) float pm[32][8];                 // per-wave row max
    __shared__ __align__(16) float ps[32][8];                 // per-wave row sum

    const int tid = threadIdx.x;
    const int wave = tid >> 6, lane = tid & 63;
    const int c = lane & 15, g = lane >> 4;
    const int bid = blockIdx.x;
    const int i = bid & 63, j = bid >> 6;
    char* ab = (char*)alpha;

    // ======= GEMM1: s[t][n] = sum_d eT[i][t][d] * vT[j][n][d]; accs in reg =====
    const bf16x8* eA = (const bf16x8*)(eT + (size_t)i * 32 * DD);
    const bf16x8* vB = (const bf16x8*)(vT + (size_t)j * 304 * DD);

    int nt[3];  bool vq[3];  int nn[3];
    #pragma unroll
    for (int q = 0; q < 3; ++q) {
        nt[q] = wave + 8 * q;            // 19 n-tiles over 8 waves
        vq[q] = (nt[q] < 19);            // wave-uniform
        nn[q] = nt[q] * 16 + c;
    }

    f32x4 acc0[3], acc1[3];
    #pragma unroll
    for (int q = 0; q < 3; ++q) {
        acc0[q] = (f32x4){0.f, 0.f, 0.f, 0.f};
        acc1[q] = (f32x4){0.f, 0.f, 0.f, 0.f};
        if (vq[q]) {                     // uniform branch
            bf16x8 b1[8];
            #pragma unroll
            for (int k = 0; k < 8; ++k)
                b1[k] = vB[(nt[q] * 16 + c) * 32 + k * 4 + g];
            #pragma unroll
            for (int k = 0; k < 8; ++k) {
                acc0[q] = __builtin_amdgcn_mfma_f32_16x16x32_bf16(
                    eA[c * 32 + k * 4 + g], b1[k], acc0[q], 0, 0, 0);
                acc1[q] = __builtin_amdgcn_mfma_f32_16x16x32_bf16(
                    eA[(16 + c) * 32 + k * 4 + g], b1[k], acc1[q], 0, 0, 0);
            }
        }
    }

    // ======= softmax over n: in-register partials -> tiny LDS table =============
    // slot s: r=s&3, hi=s>>2 -> t = hi*16 + g*4 + r
    float rowm[8], rowsum[8];
    #pragma unroll
    for (int s = 0; s < 8; ++s) {
        const int r = s & 3, hi = s >> 2;
        float m = -INFINITY;
        #pragma unroll
        for (int q = 0; q < 3; ++q) {
            float val = hi ? acc1[q][r] : acc0[q][r];
            bool ok = vq[q] && (nn[q] < NR);
            m = ok ? fmaxf(m, val) : m;
        }
        #pragma unroll
        for (int mk = 1; mk <= 8; mk <<= 1) m = fmaxf(m, __shfl_xor(m, mk, 64));
        float su = 0.f;
        #pragma unroll
        for (int q = 0; q < 3; ++q) {
            float val = hi ? acc1[q][r] : acc0[q][r];
            bool ok = vq[q] && (nn[q] < NR);
            su += ok ? __expf(val - m) : 0.f;
        }
        #pragma unroll
        for (int mk = 1; mk <= 8; mk <<= 1) su += __shfl_xor(su, mk, 64);
        rowm[s] = m; rowsum[s] = su;
    }
    if (c == 0) {
        #pragma unroll
        for (int s = 0; s < 8; ++s) {
            int t = (s >> 2) * 16 + g * 4 + (s & 3);
            pm[t][wave] = rowm[s];
            ps[t][wave] = rowsum[s];
        }
    }
    __syncthreads();

    // combine the 8 per-wave partials (redundantly in every lane; broadcast reads)
    float fm[8], fiv[8];
    #pragma unroll
    for (int s = 0; s < 8; ++s) {
        int t = (s >> 2) * 16 + g * 4 + (s & 3);
        const f32x4* pmr = (const f32x4*)&pm[t][0];
        const f32x4* psr = (const f32x4*)&ps[t][0];
        f32x4 p0 = pmr[0], p1 = pmr[1];
        f32x4 q0 = psr[0], q1 = psr[1];
        float m = fmaxf(fmaxf(fmaxf(p0[0], p0[1]), fmaxf(p0[2], p0[3])),
                        fmaxf(fmaxf(p1[0], p1[1]), fmaxf(p1[2], p1[3])));
        float su = q0[0] * __expf(p0[0] - m) + q0[1] * __expf(p0[1] - m)
                 + q0[2] * __expf(p0[2] - m) + q0[3] * __expf(p0[3] - m)
                 + q1[0] * __expf(p1[0] - m) + q1[1] * __expf(p1[1] - m)
                 + q1[2] * __expf(p1[2] - m) + q1[3] * __expf(p1[3] - m);
        fm[s] = m; fiv[s] = 1.f / su;
    }

    // ======= softmax over t (arg = 4*s_norm in (0,4] -> no max needed),
    //         in-register via xor-16/32 shuffles; write alpha bf16 swizzled ====
    #pragma unroll
    for (int q = 0; q < 3; ++q) {
        if (vq[q]) {                     // uniform
            bool colok = (nn[q] < NR);
            float ex[8];
            float colsum = 0.f;
            #pragma unroll
            for (int s = 0; s < 8; ++s) {
                const int r = s & 3, hi = s >> 2;
                float val = hi ? acc1[q][r] : acc0[q][r];
                float p = __expf(val - fm[s]) * fiv[s];       // s_norm
                bool tok = (s < 4) || (g < 2);                // t < 24
                float e4 = tok ? __expf(4.f * p) : 0.f;
                ex[s] = e4; colsum += e4;
            }
            colsum += __shfl_xor(colsum, 16, 64);
            colsum += __shfl_xor(colsum, 32, 64);
            float inv = 1.f / colsum;
            #pragma unroll
            for (int s = 0; s < 8; ++s) {
                int t = (s >> 2) * 16 + g * 4 + (s & 3);
                float av = colok ? ex[s] * inv : 0.f;
                int boff = (t * 640 + 2 * nn[q]) ^ ((t & 7) << 4);
                *(__hip_bfloat16*)(ab + boff) = __float2bfloat16(av);
            }
        }
    }
    // zero pad cols 304..319 (rows 0..31): 256 threads x 4B
    if (tid < 256) {
        int t = tid >> 3, n0 = 304 + 2 * (tid & 7);
        int boff = (t * 640 + 2 * n0) ^ ((t & 7) << 4);
        *(uint32_t*)(ab + boff) = 0u;
    }
    __syncthreads();

    // ======= GEMM2: c[t][d] = sum_n alpha[t][n]*vbf[j][d][n]; fused epilogue ===
    const bf16x8* vB2 = (const bf16x8*)(vbf + (size_t)j * DD * 320);
    const float* ei = e + (size_t)i * DD * TT;

    float ssum = 0.f;
    #pragma unroll
    for (int q = 0; q < 2; ++q) {
        int nt2 = wave + 8 * q;          // 16 d-tiles over 8 waves
        bf16x8 b2[10];
        #pragma unroll
        for (int k = 0; k < 10; ++k)
            b2[k] = vB2[(nt2 * 16 + c) * 40 + k * 4 + g];
        f32x4 A0 = {0.f, 0.f, 0.f, 0.f}, A1 = {0.f, 0.f, 0.f, 0.f};
        #pragma unroll
        for (int k = 0; k < 10; ++k) {
            int t0 = c;        // m=0 row
            int t1 = 16 + c;   // m=1 row
            bf16x8 a0 = *(const bf16x8*)(ab + ((t0 * 640 + k * 64 + g * 16) ^ ((t0 & 7) << 4)));
            bf16x8 a1f = *(const bf16x8*)(ab + ((t1 * 640 + k * 64 + g * 16) ^ ((t1 & 7) << 4)));
            A0 = __builtin_amdgcn_mfma_f32_16x16x32_bf16(a0, b2[k], A0, 0, 0, 0);
            A1 = __builtin_amdgcn_mfma_f32_16x16x32_bf16(a1f, b2[k], A1, 0, 0, 0);
        }
        // epilogue: cosine over t for this lane's d column
        int d = nt2 * 16 + c;
        const float* ed = ei + d * TT;
        float dot = 0.f, cn2 = 0.f, en2 = 0.f;
        #pragma unroll
        for (int r = 0; r < 4; ++r) {
            int t0 = g * 4 + r;
            float ev = ed[t0];
            dot = fmaf(A0[r], ev, dot);
            cn2 = fmaf(A0[r], A0[r], cn2);
            en2 = fmaf(ev, ev, en2);
            int t1 = 16 + g * 4 + r;
            float ev1 = (t1 < TT) ? ed[t1] : 0.f;
            dot = fmaf(A1[r], ev1, dot);
            cn2 = fmaf(A1[r], A1[r], cn2);
            en2 = fmaf(ev1, ev1, en2);
        }
        dot += __shfl_xor(dot, 16, 64); cn2 += __shfl_xor(cn2, 16, 64); en2 += __shfl_xor(en2, 16, 64);
        dot += __shfl_xor(dot, 32, 64); cn2 += __shfl_xor(cn2, 32, 64); en2 += __shfl_xor(en2, 32, 64);
        float R = dot / fmaxf(sqrtf(cn2) * sqrtf(en2), 1e-8f);
        ssum += __expf(5.f * R);         // 5R in [-5,5]: no max subtraction needed
    }
    // butterfly-sum over the wave (each d duplicated 4x), then cross-wave
    #pragma unroll
    for (int mk = 1; mk <= 32; mk <<= 1) ssum += __shfl_xor(ssum, mk, 64);
    if (lane == 0) ((float*)pm)[wave] = ssum;   // pm area is dead now
    __syncthreads();
    if (tid == 0) {
        float total = 0.f;
        #pragma unroll
        for (int w = 0; w < 8; ++w) total += ((float*)pm)[w];
        float lse = logf(total * 0.25f);        // /4 removes lane-quad duplication
        Smat[bid] = powf(lse, 0.2f);
    }
}

// out[0..63] = sum_j S[i][j]; out[64..127] = sum_i S[i][j]
__global__ void reduce_kernel(const float* __restrict__ Smat, float* __restrict__ out) {
    int k = threadIdx.x;   // 0..127
    float s = 0.f;
    if (k < 64) {
        int i = k;
        for (int j = 0; j < BB; ++j) s += Smat[j * 64 + i];
        out[i] = s;
    } else {
        int jq = k - 64;
        for (int i = 0; i < BB; ++i) s += Smat[jq * 64 + i];
        out[64 + jq] = s;
    }
}

extern "C" void kernel_launch(void* const* d_in, const int* in_sizes, int n_in,
                              void* d_out, int out_size, void* d_ws, size_t ws_size,
                              hipStream_t stream) {
    const float* e = (const float*)d_in[0];
    const float* v = (const float*)d_in[1];
    float* out = (float*)d_out;
    char* ws = (char*)d_ws;
    __hip_bfloat16* eT  = (__hip_bfloat16*)(ws + ET_OFF);
    __hip_bfloat16* vT  = (__hip_bfloat16*)(ws + VT_OFF);
    __hip_bfloat16* vbf = (__hip_bfloat16*)(ws + VBF_OFF);
    float* Smat = (float*)(ws + SMAT_OFF);

    conv_e_kernel<<<64, 256, 0, stream>>>(e, eT);
    conv_v_kernel<<<512, 256, 0, stream>>>(v, vT, vbf);
    pair_kernel<<<BB * BB, 512, 0, stream>>>(e, eT, vT, vbf, Smat);
    reduce_kernel<<<1, 128, 0, stream>>>(Smat, out);
}

// Round 6
// 485.014 us; speedup vs baseline: 1.2844x; 1.2844x over previous
//
#include <hip/hip_runtime.h>
#include <hip/hip_bf16.h>
#include <math.h>

#define BB 64
#define DD 256
#define TT 24
#define NR 289

typedef float f32x4 __attribute__((ext_vector_type(4)));
typedef short bf16x8 __attribute__((ext_vector_type(8)));

// ws layout (bytes)
#define ET_OFF   0ul                     // eT  [64][32][256] bf16 (t>=24 zero)   1,048,576
#define VT_OFF   1048576ul               // vT  [64][304][256] bf16 (n>=289 zero) 9,961,472
#define VBF_OFF  11010048ul              // vbf [64][256][320] bf16 (n>=289 zero) 10,485,760
#define SMAT_OFF 21495808ul              // Smat [4096] f32

// ---- convert e -> eT[i][t][d] bf16, rows t>=24 zeroed
__global__ void conv_e_kernel(const float* __restrict__ e, __hip_bfloat16* __restrict__ eT) {
    int i = blockIdx.x, d = threadIdx.x;
    const float* src = e + ((size_t)i * DD + d) * TT;
    __hip_bfloat16* dst = eT + (size_t)i * 32 * DD + d;
    #pragma unroll
    for (int t = 0; t < 32; ++t) {
        float vv = (t < TT) ? src[t] : 0.f;
        dst[(size_t)t * DD] = __float2bfloat16(vv);
    }
}

// ---- convert v -> vT[j][n][d] and vbf[j][d][n] (both bf16, padded with zeros)
__global__ __launch_bounds__(256) void conv_v_kernel(const float* __restrict__ v,
                                                     __hip_bfloat16* __restrict__ vT,
                                                     __hip_bfloat16* __restrict__ vbf) {
    __shared__ float ld[32][305];   // pitch 305: coprime with 32 -> conflict-free col reads
    int j = blockIdx.x >> 3;
    int dbase = (blockIdx.x & 7) * 32;
    int tid = threadIdx.x;
    const float* vj = v + (size_t)j * DD * NR;
    for (int r = 0; r < 32; ++r) {
        const float* row = vj + (size_t)(dbase + r) * NR;
        ld[r][tid] = row[tid];
        if (tid < 48) {
            int n = 256 + tid;
            ld[r][n] = (n < NR) ? row[n] : 0.f;
        }
    }
    __syncthreads();
    { // vT[j][n][dbase+d], coalesced 32-lane writes
        int d = tid & 31, ng = tid >> 5;
        __hip_bfloat16* base = vT + (size_t)j * 304 * DD + dbase + d;
        for (int n = ng; n < 304; n += 8)
            base[(size_t)n * DD] = __float2bfloat16(ld[d][n]);
    }
    { // vbf[j][dbase+r][n], coalesced
        __hip_bfloat16* base = vbf + ((size_t)j * DD + dbase) * 320;
        for (int idx = tid; idx < 32 * 320; idx += 256) {
            int r = idx / 320, n = idx - r * 320;
            float vv = (n < NR) ? ld[r][n] : 0.f;
            base[(size_t)r * 320 + n] = __float2bfloat16(vv);
        }
    }
}

// ---- one block (512 thr, 8 waves) per (i,j) pair; Smat[j*64+i] = S[i][j]
// In-register scores through both softmaxes; only alpha hits LDS.
// launch_bounds(512,4): VGPR cap 128 (round-5 lesson: cap 85 -> 1.9 GB spills).
__global__ __launch_bounds__(512, 4) void pair_kernel(const float* __restrict__ e,
                                                      const __hip_bfloat16* __restrict__ eT,
                                                      const __hip_bfloat16* __restrict__ vT,
                                                      const __hip_bfloat16* __restrict__ vbf,
                                                      float* __restrict__ Smat) {
    __shared__ __align__(16) __hip_bfloat16 alpha[32 * 320];  // XOR-swizzled rows
    __shared__ __align__(16) float pm[32][8];                 // per-wave row max
    __shared__ __align__(16) float ps[32][8];                 // per-wave row sum

    const int tid = threadIdx.x;
    const int wave = tid >> 6, lane = tid & 63;
    const int c = lane & 15, g = lane >> 4;
    // XCD-aware swizzle (T1): consecutive hardware bids share j otherwise get
    // split across all 8 XCDs; remap so each XCD owns 8 contiguous j-groups
    // (v[j] working set 2.4 MB < 4 MB L2). 4096 = 8*512, bijective.
    const int bid = (blockIdx.x & 7) * 512 + (blockIdx.x >> 3);
    const int i = bid & 63, j = bid >> 6;
    char* ab = (char*)alpha;

    // ======= GEMM1: s[t][n] = sum_d eT[i][t][d] * vT[j][n][d]; accs in reg =====
    const bf16x8* eA = (const bf16x8*)(eT + (size_t)i * 32 * DD);
    const bf16x8* vB = (const bf16x8*)(vT + (size_t)j * 304 * DD);

    int nt[3];  bool vq[3];  int nn[3];
    #pragma unroll
    for (int q = 0; q < 3; ++q) {
        nt[q] = wave + 8 * q;            // 19 n-tiles over 8 waves
        vq[q] = (nt[q] < 19);            // wave-uniform
        nn[q] = nt[q] * 16 + c;
    }

    f32x4 acc0[3], acc1[3];
    #pragma unroll
    for (int q = 0; q < 3; ++q) {
        acc0[q] = (f32x4){0.f, 0.f, 0.f, 0.f};
        acc1[q] = (f32x4){0.f, 0.f, 0.f, 0.f};
        if (vq[q]) {                     // uniform branch
            bf16x8 b1[8];
            #pragma unroll
            for (int k = 0; k < 8; ++k)
                b1[k] = vB[(nt[q] * 16 + c) * 32 + k * 4 + g];
            #pragma unroll
            for (int k = 0; k < 8; ++k) {
                acc0[q] = __builtin_amdgcn_mfma_f32_16x16x32_bf16(
                    eA[c * 32 + k * 4 + g], b1[k], acc0[q], 0, 0, 0);
                acc1[q] = __builtin_amdgcn_mfma_f32_16x16x32_bf16(
                    eA[(16 + c) * 32 + k * 4 + g], b1[k], acc1[q], 0, 0, 0);
            }
        }
    }

    // ======= softmax over n: in-register partials -> tiny LDS table =============
    // slot s: r=s&3, hi=s>>2 -> t = hi*16 + g*4 + r
    float rowm[8], rowsum[8];
    #pragma unroll
    for (int s = 0; s < 8; ++s) {
        const int r = s & 3, hi = s >> 2;
        float m = -INFINITY;
        #pragma unroll
        for (int q = 0; q < 3; ++q) {
            float val = hi ? acc1[q][r] : acc0[q][r];
            bool ok = vq[q] && (nn[q] < NR);
            m = ok ? fmaxf(m, val) : m;
        }
        #pragma unroll
        for (int mk = 1; mk <= 8; mk <<= 1) m = fmaxf(m, __shfl_xor(m, mk, 64));
        float su = 0.f;
        #pragma unroll
        for (int q = 0; q < 3; ++q) {
            float val = hi ? acc1[q][r] : acc0[q][r];
            bool ok = vq[q] && (nn[q] < NR);
            su += ok ? __expf(val - m) : 0.f;
        }
        #pragma unroll
        for (int mk = 1; mk <= 8; mk <<= 1) su += __shfl_xor(su, mk, 64);
        rowm[s] = m; rowsum[s] = su;
    }
    if (c == 0) {
        #pragma unroll
        for (int s = 0; s < 8; ++s) {
            int t = (s >> 2) * 16 + g * 4 + (s & 3);
            pm[t][wave] = rowm[s];
            ps[t][wave] = rowsum[s];
        }
    }
    __syncthreads();

    // combine the 8 per-wave partials (redundantly in every lane; broadcast reads)
    float fm[8], fiv[8];
    #pragma unroll
    for (int s = 0; s < 8; ++s) {
        int t = (s >> 2) * 16 + g * 4 + (s & 3);
        const f32x4* pmr = (const f32x4*)&pm[t][0];
        const f32x4* psr = (const f32x4*)&ps[t][0];
        f32x4 p0 = pmr[0], p1 = pmr[1];
        f32x4 q0 = psr[0], q1 = psr[1];
        float m = fmaxf(fmaxf(fmaxf(p0[0], p0[1]), fmaxf(p0[2], p0[3])),
                        fmaxf(fmaxf(p1[0], p1[1]), fmaxf(p1[2], p1[3])));
        float su = q0[0] * __expf(p0[0] - m) + q0[1] * __expf(p0[1] - m)
                 + q0[2] * __expf(p0[2] - m) + q0[3] * __expf(p0[3] - m)
                 + q1[0] * __expf(p1[0] - m) + q1[1] * __expf(p1[1] - m)
                 + q1[2] * __expf(p1[2] - m) + q1[3] * __expf(p1[3] - m);
        fm[s] = m; fiv[s] = 1.f / su;
    }

    // ======= softmax over t (arg = 4*s_norm in (0,4] -> no max needed),
    //         in-register via xor-16/32 shuffles; write alpha bf16 swizzled ====
    #pragma unroll
    for (int q = 0; q < 3; ++q) {
        if (vq[q]) {                     // uniform
            bool colok = (nn[q] < NR);
            float ex[8];
            float colsum = 0.f;
            #pragma unroll
            for (int s = 0; s < 8; ++s) {
                const int r = s & 3, hi = s >> 2;
                float val = hi ? acc1[q][r] : acc0[q][r];
                float p = __expf(val - fm[s]) * fiv[s];       // s_norm
                bool tok = (s < 4) || (g < 2);                // t < 24
                float e4 = tok ? __expf(4.f * p) : 0.f;
                ex[s] = e4; colsum += e4;
            }
            colsum += __shfl_xor(colsum, 16, 64);
            colsum += __shfl_xor(colsum, 32, 64);
            float inv = 1.f / colsum;
            #pragma unroll
            for (int s = 0; s < 8; ++s) {
                int t = (s >> 2) * 16 + g * 4 + (s & 3);
                float av = colok ? ex[s] * inv : 0.f;
                int boff = (t * 640 + 2 * nn[q]) ^ ((t & 7) << 4);
                *(__hip_bfloat16*)(ab + boff) = __float2bfloat16(av);
            }
        }
    }
    // zero pad cols 304..319 (rows 0..31): 256 threads x 4B
    if (tid < 256) {
        int t = tid >> 3, n0 = 304 + 2 * (tid & 7);
        int boff = (t * 640 + 2 * n0) ^ ((t & 7) << 4);
        *(uint32_t*)(ab + boff) = 0u;
    }
    __syncthreads();

    // ======= GEMM2: c[t][d] = sum_n alpha[t][n]*vbf[j][d][n]; fused epilogue ===
    const bf16x8* vB2 = (const bf16x8*)(vbf + (size_t)j * DD * 320);
    const float* ei = e + (size_t)i * DD * TT;

    float ssum = 0.f;
    #pragma unroll
    for (int q = 0; q < 2; ++q) {
        int nt2 = wave + 8 * q;          // 16 d-tiles over 8 waves
        bf16x8 b2[10];
        #pragma unroll
        for (int k = 0; k < 10; ++k)
            b2[k] = vB2[(nt2 * 16 + c) * 40 + k * 4 + g];
        f32x4 A0 = {0.f, 0.f, 0.f, 0.f}, A1 = {0.f, 0.f, 0.f, 0.f};
        #pragma unroll
        for (int k = 0; k < 10; ++k) {
            int t0 = c;        // m=0 row
            int t1 = 16 + c;   // m=1 row
            bf16x8 a0 = *(const bf16x8*)(ab + ((t0 * 640 + k * 64 + g * 16) ^ ((t0 & 7) << 4)));
            bf16x8 a1f = *(const bf16x8*)(ab + ((t1 * 640 + k * 64 + g * 16) ^ ((t1 & 7) << 4)));
            A0 = __builtin_amdgcn_mfma_f32_16x16x32_bf16(a0, b2[k], A0, 0, 0, 0);
            A1 = __builtin_amdgcn_mfma_f32_16x16x32_bf16(a1f, b2[k], A1, 0, 0, 0);
        }
        // epilogue: cosine over t for this lane's d column
        int d = nt2 * 16 + c;
        const float* ed = ei + d * TT;
        float dot = 0.f, cn2 = 0.f, en2 = 0.f;
        #pragma unroll
        for (int r = 0; r < 4; ++r) {
            int t0 = g * 4 + r;
            float ev = ed[t0];
            dot = fmaf(A0[r], ev, dot);
            cn2 = fmaf(A0[r], A0[r], cn2);
            en2 = fmaf(ev, ev, en2);
            int t1 = 16 + g * 4 + r;
            float ev1 = (t1 < TT) ? ed[t1] : 0.f;
            dot = fmaf(A1[r], ev1, dot);
            cn2 = fmaf(A1[r], A1[r], cn2);
            en2 = fmaf(ev1, ev1, en2);
        }
        dot += __shfl_xor(dot, 16, 64); cn2 += __shfl_xor(cn2, 16, 64); en2 += __shfl_xor(en2, 16, 64);
        dot += __shfl_xor(dot, 32, 64); cn2 += __shfl_xor(cn2, 32, 64); en2 += __shfl_xor(en2, 32, 64);
        float R = dot / fmaxf(sqrtf(cn2) * sqrtf(en2), 1e-8f);
        ssum += __expf(5.f * R);         // 5R in [-5,5]: no max subtraction needed
    }
    // butterfly-sum over the wave (each d duplicated 4x), then cross-wave
    #pragma unroll
    for (int mk = 1; mk <= 32; mk <<= 1) ssum += __shfl_xor(ssum, mk, 64);
    if (lane == 0) ((float*)pm)[wave] = ssum;   // pm area is dead now
    __syncthreads();
    if (tid == 0) {
        float total = 0.f;
        #pragma unroll
        for (int w = 0; w < 8; ++w) total += ((float*)pm)[w];
        float lse = logf(total * 0.25f);        // /4 removes lane-quad duplication
        Smat[bid] = powf(lse, 0.2f);
    }
}

// out[0..63] = sum_j S[i][j]; out[64..127] = sum_i S[i][j]
__global__ void reduce_kernel(const float* __restrict__ Smat, float* __restrict__ out) {
    int k = threadIdx.x;   // 0..127
    float s = 0.f;
    if (k < 64) {
        int i = k;
        for (int j = 0; j < BB; ++j) s += Smat[j * 64 + i];
        out[i] = s;
    } else {
        int jq = k - 64;
        for (int i = 0; i < BB; ++i) s += Smat[jq * 64 + i];
        out[64 + jq] = s;
    }
}

extern "C" void kernel_launch(void* const* d_in, const int* in_sizes, int n_in,
                              void* d_out, int out_size, void* d_ws, size_t ws_size,
                              hipStream_t stream) {
    const float* e = (const float*)d_in[0];
    const float* v = (const float*)d_in[1];
    float* out = (float*)d_out;
    char* ws = (char*)d_ws;
    __hip_bfloat16* eT  = (__hip_bfloat16*)(ws + ET_OFF);
    __hip_bfloat16* vT  = (__hip_bfloat16*)(ws + VT_OFF);
    __hip_bfloat16* vbf = (__hip_bfloat16*)(ws + VBF_OFF);
    float* Smat = (float*)(ws + SMAT_OFF);

    conv_e_kernel<<<64, 256, 0, stream>>>(e, eT);
    conv_v_kernel<<<512, 256, 0, stream>>>(v, vT, vbf);
    pair_kernel<<<BB * BB, 512, 0, stream>>>(e, eT, vT, vbf, Smat);
    reduce_kernel<<<1, 128, 0, stream>>>(Smat, out);
}

// Round 7
// 330.730 us; speedup vs baseline: 1.8836x; 1.4665x over previous
//
#include <hip/hip_runtime.h>
#include <hip/hip_bf16.h>
#include <math.h>

#define BB 64
#define DD 256
#define TT 24
#define NR 289

typedef float f32x4 __attribute__((ext_vector_type(4)));
typedef short bf16x8 __attribute__((ext_vector_type(8)));

// ws layout (bytes)
#define ET_OFF   0ul                     // eT  [64][32][256] bf16 (t>=24 zero)   1,048,576
#define VT_OFF   1048576ul               // vT  [64][304][256] bf16 (n>=289 zero) 9,961,472
#define VBF_OFF  11010048ul              // vbf [64][256][320] bf16 (n>=289 zero) 10,485,760
#define SMAT_OFF 21495808ul              // Smat [4096] f32

// ---- convert e -> eT[i][t][d] bf16, rows t>=24 zeroed
__global__ void conv_e_kernel(const float* __restrict__ e, __hip_bfloat16* __restrict__ eT) {
    int i = blockIdx.x, d = threadIdx.x;
    const float* src = e + ((size_t)i * DD + d) * TT;
    __hip_bfloat16* dst = eT + (size_t)i * 32 * DD + d;
    #pragma unroll
    for (int t = 0; t < 32; ++t) {
        float vv = (t < TT) ? src[t] : 0.f;
        dst[(size_t)t * DD] = __float2bfloat16(vv);
    }
}

// ---- convert v -> vT[j][n][d] and vbf[j][d][n] (both bf16, padded with zeros)
__global__ __launch_bounds__(256) void conv_v_kernel(const float* __restrict__ v,
                                                     __hip_bfloat16* __restrict__ vT,
                                                     __hip_bfloat16* __restrict__ vbf) {
    __shared__ float ld[32][305];   // pitch 305: coprime with 32 -> conflict-free col reads
    int j = blockIdx.x >> 3;
    int dbase = (blockIdx.x & 7) * 32;
    int tid = threadIdx.x;
    const float* vj = v + (size_t)j * DD * NR;
    for (int r = 0; r < 32; ++r) {
        const float* row = vj + (size_t)(dbase + r) * NR;
        ld[r][tid] = row[tid];
        if (tid < 48) {
            int n = 256 + tid;
            ld[r][n] = (n < NR) ? row[n] : 0.f;
        }
    }
    __syncthreads();
    { // vT[j][n][dbase+d], coalesced 32-lane writes
        int d = tid & 31, ng = tid >> 5;
        __hip_bfloat16* base = vT + (size_t)j * 304 * DD + dbase + d;
        for (int n = ng; n < 304; n += 8)
            base[(size_t)n * DD] = __float2bfloat16(ld[d][n]);
    }
    { // vbf[j][dbase+r][n], coalesced
        __hip_bfloat16* base = vbf + ((size_t)j * DD + dbase) * 320;
        for (int idx = tid; idx < 32 * 320; idx += 256) {
            int r = idx / 320, n = idx - r * 320;
            float vv = (n < NR) ? ld[r][n] : 0.f;
            base[(size_t)r * 320 + n] = __float2bfloat16(vv);
        }
    }
}

// ---- one block (256 thr) per (i,j) pair; Smat[j*64+i] = S[i][j]
// Round-4 structure (proven 60 VGPR, spill-free). Changes vs round 4:
//  * launch_bounds(256,6): cap 85 > natural 60 -> no spills, 6 blocks/CU.
//  * XCD-aware bid swizzle: 8 j's per XCD -> vT/vbf L2-resident.
//  * pad-only zeroing (rows 24-31, swizzled cols 304-319), no extra barrier.
__global__ __launch_bounds__(256, 6) void pair_kernel(const float* __restrict__ e,
                                                      const __hip_bfloat16* __restrict__ eT,
                                                      const __hip_bfloat16* __restrict__ vT,
                                                      const __hip_bfloat16* __restrict__ vbf,
                                                      float* __restrict__ Smat) {
    __shared__ __align__(16) __hip_bfloat16 alpha[32 * 320];   // 20480 B, XOR-swizzled rows

    const int tid = threadIdx.x;
    const int wave = tid >> 6, lane = tid & 63;
    const int c = lane & 15, g = lane >> 4;
    // XCD swizzle (T1): bijective (4096 = 8*512); each XCD serves 8 j's (2.6 MB < 4 MB L2)
    const int bid = (blockIdx.x & 7) * 512 + (blockIdx.x >> 3);
    const int i = bid & 63, j = bid >> 6;

    char* ab = (char*)alpha;

    // zero ONLY the pad regions GEMM2 reads (NaN-garbage hazard):
    //  rows 24..31 full (A rows t>=24 must be 0 for the cn2 accumulation),
    //  cols 304..319 rows 0..23 (never written by GEMM1; B side is 0 but NaN*0=NaN).
    {
        uint32_t* rz = (uint32_t*)(ab + 24 * 640);   // 8 rows * 640 B, swizzle-invariant
        #pragma unroll
        for (int q = 0; q < 5; ++q) rz[tid + q * 256] = 0u;
        int t = tid >> 3, n0 = 304 + 2 * (tid & 7);  // 32 rows x 16 cols, swizzled
        int boff = (t * 640 + 2 * n0) ^ ((t & 7) << 4);
        *(uint32_t*)(ab + boff) = 0u;
    }
    // no barrier: pad region is disjoint from all pre-GEMM2 writes/reads and is
    // only read in GEMM2, which is two barriers away.

    // ================= GEMM1: s[t][n] = sum_d eT[i][t][d] * v[j][d][n] ==========
    const bf16x8* eA = (const bf16x8*)(eT + (size_t)i * 32 * DD);
    bf16x8 a1[2][8];
    #pragma unroll
    for (int m = 0; m < 2; ++m)
        #pragma unroll
        for (int k = 0; k < 8; ++k)
            a1[m][k] = eA[(m * 16 + c) * 32 + k * 4 + g];

    const bf16x8* vB = (const bf16x8*)(vT + (size_t)j * 304 * DD);
    for (int nt = wave; nt < 19; nt += 4) {
        bf16x8 b1[8];
        #pragma unroll
        for (int k = 0; k < 8; ++k)
            b1[k] = vB[(nt * 16 + c) * 32 + k * 4 + g];
        f32x4 acc0 = {0.f, 0.f, 0.f, 0.f}, acc1 = {0.f, 0.f, 0.f, 0.f};
        #pragma unroll
        for (int k = 0; k < 8; ++k) {
            acc0 = __builtin_amdgcn_mfma_f32_16x16x32_bf16(a1[0][k], b1[k], acc0, 0, 0, 0);
            acc1 = __builtin_amdgcn_mfma_f32_16x16x32_bf16(a1[1][k], b1[k], acc1, 0, 0, 0);
        }
        // store scores as bf16 into the swizzled alpha buffer
        #pragma unroll
        for (int r = 0; r < 4; ++r) {
            int t0 = g * 4 + r;
            int b0 = ((t0 * 320 + nt * 16 + c) * 2) ^ ((t0 & 7) << 4);
            *(__hip_bfloat16*)(ab + b0) = __float2bfloat16(acc0[r]);
            int t1 = 16 + g * 4 + r;
            if (t1 < TT) {
                int b1o = ((t1 * 320 + nt * 16 + c) * 2) ^ ((t1 & 7) << 4);
                *(__hip_bfloat16*)(ab + b1o) = __float2bfloat16(acc1[r]);
            }
        }
    }
    __syncthreads();

    // ============ softmax over n, in place on bf16 rows (wave owns 6 t-rows) ====
    #pragma unroll
    for (int tt = 0; tt < 6; ++tt) {
        int t = wave * 6 + tt;
        int base = t * 640, sw = (t & 7) << 4;
        float vls[5];
        #pragma unroll
        for (int k5 = 0; k5 < 5; ++k5) {
            int n = k5 * 64 + lane;
            vls[k5] = (n < NR)
                ? __bfloat162float(*(const __hip_bfloat16*)(ab + ((base + 2 * n) ^ sw)))
                : -INFINITY;
        }
        float m = vls[0];
        #pragma unroll
        for (int k5 = 1; k5 < 5; ++k5) m = fmaxf(m, vls[k5]);
        #pragma unroll
        for (int mk = 32; mk >= 1; mk >>= 1) m = fmaxf(m, __shfl_xor(m, mk, 64));
        float sum = 0.f;
        #pragma unroll
        for (int k5 = 0; k5 < 5; ++k5) { vls[k5] = __expf(vls[k5] - m); sum += vls[k5]; }
        #pragma unroll
        for (int mk = 32; mk >= 1; mk >>= 1) sum += __shfl_xor(sum, mk, 64);
        float inv = 1.f / sum;
        #pragma unroll
        for (int k5 = 0; k5 < 5; ++k5) {
            int n = k5 * 64 + lane;
            if (n < NR)
                *(__hip_bfloat16*)(ab + ((base + 2 * n) ^ sw)) = __float2bfloat16(vls[k5] * inv);
        }
    }
    __syncthreads();

    // ====== softmax over t of G1*s_norm, in place per column (thread <-> n) =====
    for (int p = 0; p < 2; ++p) {
        int n = p * 256 + tid;
        if (n < NR) {
            float vals[TT];
            #pragma unroll
            for (int t = 0; t < TT; ++t)
                vals[t] = __bfloat162float(
                    *(const __hip_bfloat16*)(ab + ((t * 640 + 2 * n) ^ ((t & 7) << 4))));
            float m = vals[0];
            #pragma unroll
            for (int t = 1; t < TT; ++t) m = fmaxf(m, vals[t]);
            m *= 4.0f;
            float sum = 0.f;
            #pragma unroll
            for (int t = 0; t < TT; ++t) { vals[t] = __expf(4.0f * vals[t] - m); sum += vals[t]; }
            float inv = 1.f / sum;
            #pragma unroll
            for (int t = 0; t < TT; ++t)
                *(__hip_bfloat16*)(ab + ((t * 640 + 2 * n) ^ ((t & 7) << 4))) =
                    __float2bfloat16(vals[t] * inv);
        }
    }
    __syncthreads();

    // ====== GEMM2: c[t][d] = sum_n alpha[t][n]*v[d][n]; fused epilogue ==========
    bf16x8 a2[2][10];
    {
        #pragma unroll
        for (int m = 0; m < 2; ++m) {
            int t = m * 16 + c;
            int sw = (t & 7) << 4;
            #pragma unroll
            for (int k = 0; k < 10; ++k) {
                int boff = (t * 640 + k * 64 + g * 16) ^ sw;
                a2[m][k] = *(const bf16x8*)(ab + boff);
            }
        }
    }
    const bf16x8* vB2 = (const bf16x8*)(vbf + (size_t)j * DD * 320);
    const float* ei = e + (size_t)i * DD * TT;

    float mrun = -INFINITY, srun = 0.f;
    for (int q = 0; q < 4; ++q) {
        int nt = wave + q * 4;   // d-tile
        bf16x8 b2[10];
        #pragma unroll
        for (int k = 0; k < 10; ++k)
            b2[k] = vB2[(nt * 16 + c) * 40 + k * 4 + g];
        f32x4 acc0 = {0.f, 0.f, 0.f, 0.f}, acc1 = {0.f, 0.f, 0.f, 0.f};
        #pragma unroll
        for (int k = 0; k < 10; ++k) {
            acc0 = __builtin_amdgcn_mfma_f32_16x16x32_bf16(a2[0][k], b2[k], acc0, 0, 0, 0);
            acc1 = __builtin_amdgcn_mfma_f32_16x16x32_bf16(a2[1][k], b2[k], acc1, 0, 0, 0);
        }
        // epilogue: cosine over t for this lane's d column
        int d = nt * 16 + c;
        const float* ed = ei + d * TT;
        float dot = 0.f, cn2 = 0.f, en2 = 0.f;
        #pragma unroll
        for (int r = 0; r < 4; ++r) {
            int t0 = g * 4 + r;
            float ev = ed[t0];
            dot = fmaf(acc0[r], ev, dot);
            cn2 = fmaf(acc0[r], acc0[r], cn2);
            en2 = fmaf(ev, ev, en2);
            int t1 = 16 + g * 4 + r;
            float ev1 = (t1 < TT) ? ed[t1] : 0.f;
            dot = fmaf(acc1[r], ev1, dot);
            cn2 = fmaf(acc1[r], acc1[r], cn2);
            en2 = fmaf(ev1, ev1, en2);
        }
        dot += __shfl_xor(dot, 16, 64); cn2 += __shfl_xor(cn2, 16, 64); en2 += __shfl_xor(en2, 16, 64);
        dot += __shfl_xor(dot, 32, 64); cn2 += __shfl_xor(cn2, 32, 64); en2 += __shfl_xor(en2, 32, 64);
        float R = dot / fmaxf(sqrtf(cn2) * sqrtf(en2), 1e-8f);
        float y = 5.0f * R;
        if (y > mrun) { srun = srun * __expf(mrun - y) + 1.f; mrun = y; }
        else          { srun += __expf(y - mrun); }
    }

    // LSE: wave butterfly (each d duplicated 4x within a wave), then cross-wave
    #pragma unroll
    for (int mk = 1; mk <= 32; mk <<= 1) {
        float mo = __shfl_xor(mrun, mk, 64);
        float so = __shfl_xor(srun, mk, 64);
        float mn = fmaxf(mrun, mo);
        srun = srun * __expf(mrun - mn) + so * __expf(mo - mn);
        mrun = mn;
    }
    // reuse alpha LDS for the 8-float cross-wave scratch (alpha no longer needed)
    float* redm = (float*)alpha;       // [4]
    float* reds = (float*)alpha + 4;   // [4]
    __syncthreads();                   // all waves done reading a2
    if (lane == 0) { redm[wave] = mrun; reds[wave] = srun; }
    __syncthreads();
    if (tid == 0) {
        float mt = fmaxf(fmaxf(redm[0], redm[1]), fmaxf(redm[2], redm[3]));
        float st = 0.f;
        #pragma unroll
        for (int w = 0; w < 4; ++w) st += reds[w] * __expf(redm[w] - mt);
        float lse = mt + logf(st * 0.25f);   // /4 removes lane-quad duplication
        Smat[bid] = powf(lse, 0.2f);
    }
}

// out[0..63] = sum_j S[i][j]; out[64..127] = sum_i S[i][j]
__global__ void reduce_kernel(const float* __restrict__ Smat, float* __restrict__ out) {
    int k = threadIdx.x;   // 0..127
    float s = 0.f;
    if (k < 64) {
        int i = k;
        for (int j = 0; j < BB; ++j) s += Smat[j * 64 + i];
        out[i] = s;
    } else {
        int jq = k - 64;
        for (int i = 0; i < BB; ++i) s += Smat[jq * 64 + i];
        out[64 + jq] = s;
    }
}

extern "C" void kernel_launch(void* const* d_in, const int* in_sizes, int n_in,
                              void* d_out, int out_size, void* d_ws, size_t ws_size,
                              hipStream_t stream) {
    const float* e = (const float*)d_in[0];
    const float* v = (const float*)d_in[1];
    float* out = (float*)d_out;
    char* ws = (char*)d_ws;
    __hip_bfloat16* eT  = (__hip_bfloat16*)(ws + ET_OFF);
    __hip_bfloat16* vT  = (__hip_bfloat16*)(ws + VT_OFF);
    __hip_bfloat16* vbf = (__hip_bfloat16*)(ws + VBF_OFF);
    float* Smat = (float*)(ws + SMAT_OFF);

    conv_e_kernel<<<64, 256, 0, stream>>>(e, eT);
    conv_v_kernel<<<512, 256, 0, stream>>>(v, vT, vbf);
    pair_kernel<<<BB * BB, 256, 0, stream>>>(e, eT, vT, vbf, Smat);
    reduce_kernel<<<1, 128, 0, stream>>>(Smat, out);
}

// Round 8
// 328.284 us; speedup vs baseline: 1.8976x; 1.0075x over previous
//
#include <hip/hip_runtime.h>
#include <hip/hip_bf16.h>
#include <math.h>

#define BB 64
#define DD 256
#define TT 24
#define NR 289

typedef float f32x4 __attribute__((ext_vector_type(4)));
typedef short bf16x8 __attribute__((ext_vector_type(8)));

// ws layout (bytes)
#define ET_OFF   0ul                     // eT  [64][32][256] bf16 (t>=24 zero)   1,048,576
#define VT_OFF   1048576ul               // vT  [64][304][256] bf16 (n>=289 zero) 9,961,472
#define VBF_OFF  11010048ul              // vbf [64][256][320] bf16 (n>=289 zero) 10,485,760
#define SMAT_OFF 21495808ul              // Smat [4096] f32

// ---- convert e -> eT[i][t][d] bf16, rows t>=24 zeroed
__global__ void conv_e_kernel(const float* __restrict__ e, __hip_bfloat16* __restrict__ eT) {
    int i = blockIdx.x, d = threadIdx.x;
    const float* src = e + ((size_t)i * DD + d) * TT;
    __hip_bfloat16* dst = eT + (size_t)i * 32 * DD + d;
    #pragma unroll
    for (int t = 0; t < 32; ++t) {
        float vv = (t < TT) ? src[t] : 0.f;
        dst[(size_t)t * DD] = __float2bfloat16(vv);
    }
}

// ---- convert v -> vT[j][n][d] and vbf[j][d][n] (both bf16, padded with zeros)
__global__ __launch_bounds__(256) void conv_v_kernel(const float* __restrict__ v,
                                                     __hip_bfloat16* __restrict__ vT,
                                                     __hip_bfloat16* __restrict__ vbf) {
    __shared__ float ld[32][305];   // pitch 305: coprime with 32 -> conflict-free col reads
    int j = blockIdx.x >> 3;
    int dbase = (blockIdx.x & 7) * 32;
    int tid = threadIdx.x;
    const float* vj = v + (size_t)j * DD * NR;
    for (int r = 0; r < 32; ++r) {
        const float* row = vj + (size_t)(dbase + r) * NR;
        ld[r][tid] = row[tid];
        if (tid < 48) {
            int n = 256 + tid;
            ld[r][n] = (n < NR) ? row[n] : 0.f;
        }
    }
    __syncthreads();
    { // vT[j][n][dbase+d], coalesced 32-lane writes
        int d = tid & 31, ng = tid >> 5;
        __hip_bfloat16* base = vT + (size_t)j * 304 * DD + dbase + d;
        for (int n = ng; n < 304; n += 8)
            base[(size_t)n * DD] = __float2bfloat16(ld[d][n]);
    }
    { // vbf[j][dbase+r][n], coalesced
        __hip_bfloat16* base = vbf + ((size_t)j * DD + dbase) * 320;
        for (int idx = tid; idx < 32 * 320; idx += 256) {
            int r = idx / 320, n = idx - r * 320;
            float vv = (n < NR) ? ld[r][n] : 0.f;
            base[(size_t)r * 320 + n] = __float2bfloat16(vv);
        }
    }
}

// ---- one block (256 thr) per (i,j) pair; Smat[j*64+i] = S[i][j]
// Round-4 structure. Unified VGPR+AGPR demand ~100-125 -> ONLY cap 128 is
// spill-free: launch_bounds(256,4). Latency attacked via XCD swizzle (L2-
// resident v[j]) + double-buffered B fragments + early b2 prefetch.
__global__ __launch_bounds__(256, 4) void pair_kernel(const float* __restrict__ e,
                                                      const __hip_bfloat16* __restrict__ eT,
                                                      const __hip_bfloat16* __restrict__ vT,
                                                      const __hip_bfloat16* __restrict__ vbf,
                                                      float* __restrict__ Smat) {
    __shared__ __align__(16) __hip_bfloat16 alpha[32 * 320];   // 20480 B, XOR-swizzled rows

    const int tid = threadIdx.x;
    const int wave = tid >> 6, lane = tid & 63;
    const int c = lane & 15, g = lane >> 4;
    // XCD swizzle (T1): bijective (4096 = 8*512); each XCD serves 8 j's (2.6 MB < 4 MB L2)
    const int bid = (blockIdx.x & 7) * 512 + (blockIdx.x >> 3);
    const int i = bid & 63, j = bid >> 6;

    char* ab = (char*)alpha;

    // zero ONLY the pad regions GEMM2 reads (NaN-garbage hazard):
    //  rows 24..31 full; cols 304..319 of all rows (swizzled).
    {
        uint32_t* rz = (uint32_t*)(ab + 24 * 640);   // 8 rows * 640 B, swizzle-invariant region
        #pragma unroll
        for (int q = 0; q < 5; ++q) rz[tid + q * 256] = 0u;
        int t = tid >> 3, n0 = 304 + 2 * (tid & 7);  // 32 rows x 16 cols, swizzled
        int boff = (t * 640 + 2 * n0) ^ ((t & 7) << 4);
        *(uint32_t*)(ab + boff) = 0u;
    }
    // no barrier needed: pad region is only read in GEMM2, two barriers away.

    // ================= GEMM1: s[t][n] = sum_d eT[i][t][d] * v[j][d][n] ==========
    const bf16x8* eA = (const bf16x8*)(eT + (size_t)i * 32 * DD);
    bf16x8 a1[2][8];
    #pragma unroll
    for (int m = 0; m < 2; ++m)
        #pragma unroll
        for (int k = 0; k < 8; ++k)
            a1[m][k] = eA[(m * 16 + c) * 32 + k * 4 + g];

    const bf16x8* vB = (const bf16x8*)(vT + (size_t)j * 304 * DD);
    bf16x8 b1A[8], b1B[8];
    #pragma unroll
    for (int k = 0; k < 8; ++k)                 // prefetch tile nt = wave
        b1A[k] = vB[(wave * 16 + c) * 32 + k * 4 + g];

    #pragma unroll
    for (int q = 0; q < 5; ++q) {               // fully unrolled -> static buffer select
        int nt = wave + q * 4;
        if (nt < 19) {                          // wave-uniform
            const bf16x8* cur = (q & 1) ? b1B : b1A;
            bf16x8*       nxt = (q & 1) ? b1A : b1B;
            int ntn = nt + 4;
            if (ntn < 19) {                     // issue next tile's loads first
                #pragma unroll
                for (int k = 0; k < 8; ++k)
                    nxt[k] = vB[(ntn * 16 + c) * 32 + k * 4 + g];
            }
            f32x4 acc0 = {0.f, 0.f, 0.f, 0.f}, acc1 = {0.f, 0.f, 0.f, 0.f};
            #pragma unroll
            for (int k = 0; k < 8; ++k) {
                acc0 = __builtin_amdgcn_mfma_f32_16x16x32_bf16(a1[0][k], cur[k], acc0, 0, 0, 0);
                acc1 = __builtin_amdgcn_mfma_f32_16x16x32_bf16(a1[1][k], cur[k], acc1, 0, 0, 0);
            }
            // store scores as bf16 into the swizzled alpha buffer
            #pragma unroll
            for (int r = 0; r < 4; ++r) {
                int t0 = g * 4 + r;
                int b0 = ((t0 * 320 + nt * 16 + c) * 2) ^ ((t0 & 7) << 4);
                *(__hip_bfloat16*)(ab + b0) = __float2bfloat16(acc0[r]);
                int t1 = 16 + g * 4 + r;
                if (t1 < TT) {
                    int b1o = ((t1 * 320 + nt * 16 + c) * 2) ^ ((t1 & 7) << 4);
                    *(__hip_bfloat16*)(ab + b1o) = __float2bfloat16(acc1[r]);
                }
            }
        }
    }

    // early prefetch of GEMM2's first B tile (depends only on j) — its latency
    // hides under the softmax phases. Held in 40 VGPRs through softmax (budget ok).
    const bf16x8* vB2 = (const bf16x8*)(vbf + (size_t)j * DD * 320);
    bf16x8 b2A[10], b2B[10];
    #pragma unroll
    for (int k = 0; k < 10; ++k)
        b2A[k] = vB2[(wave * 16 + c) * 40 + k * 4 + g];

    __syncthreads();

    // ============ softmax over n, in place on bf16 rows (wave owns 6 t-rows) ====
    #pragma unroll
    for (int tt = 0; tt < 6; ++tt) {
        int t = wave * 6 + tt;
        int base = t * 640, sw = (t & 7) << 4;
        float vls[5];
        #pragma unroll
        for (int k5 = 0; k5 < 5; ++k5) {
            int n = k5 * 64 + lane;
            vls[k5] = (n < NR)
                ? __bfloat162float(*(const __hip_bfloat16*)(ab + ((base + 2 * n) ^ sw)))
                : -INFINITY;
        }
        float m = vls[0];
        #pragma unroll
        for (int k5 = 1; k5 < 5; ++k5) m = fmaxf(m, vls[k5]);
        #pragma unroll
        for (int mk = 32; mk >= 1; mk >>= 1) m = fmaxf(m, __shfl_xor(m, mk, 64));
        float sum = 0.f;
        #pragma unroll
        for (int k5 = 0; k5 < 5; ++k5) { vls[k5] = __expf(vls[k5] - m); sum += vls[k5]; }
        #pragma unroll
        for (int mk = 32; mk >= 1; mk >>= 1) sum += __shfl_xor(sum, mk, 64);
        float inv = 1.f / sum;
        #pragma unroll
        for (int k5 = 0; k5 < 5; ++k5) {
            int n = k5 * 64 + lane;
            if (n < NR)
                *(__hip_bfloat16*)(ab + ((base + 2 * n) ^ sw)) = __float2bfloat16(vls[k5] * inv);
        }
    }
    __syncthreads();

    // ====== softmax over t of G1*s_norm, in place per column (thread <-> n) =====
    for (int p = 0; p < 2; ++p) {
        int n = p * 256 + tid;
        if (n < NR) {
            float vals[TT];
            #pragma unroll
            for (int t = 0; t < TT; ++t)
                vals[t] = __bfloat162float(
                    *(const __hip_bfloat16*)(ab + ((t * 640 + 2 * n) ^ ((t & 7) << 4))));
            float m = vals[0];
            #pragma unroll
            for (int t = 1; t < TT; ++t) m = fmaxf(m, vals[t]);
            m *= 4.0f;
            float sum = 0.f;
            #pragma unroll
            for (int t = 0; t < TT; ++t) { vals[t] = __expf(4.0f * vals[t] - m); sum += vals[t]; }
            float inv = 1.f / sum;
            #pragma unroll
            for (int t = 0; t < TT; ++t)
                *(__hip_bfloat16*)(ab + ((t * 640 + 2 * n) ^ ((t & 7) << 4))) =
                    __float2bfloat16(vals[t] * inv);
        }
    }
    __syncthreads();

    // ====== GEMM2: c[t][d] = sum_n alpha[t][n]*v[d][n]; fused epilogue ==========
    // a2 fragments read from LDS inside the k-loop (MFMA-covered) to keep regs
    // for the b2 double-buffer.
    const float* ei = e + (size_t)i * DD * TT;

    float mrun = -INFINITY, srun = 0.f;
    #pragma unroll
    for (int q = 0; q < 4; ++q) {               // fully unrolled -> static buffer select
        int nt = wave + q * 4;   // d-tile
        const bf16x8* cur = (q & 1) ? b2B : b2A;
        bf16x8*       nxt = (q & 1) ? b2A : b2B;
        if (q < 3) {                            // issue next tile's loads first
            int ntn = nt + 4;
            #pragma unroll
            for (int k = 0; k < 10; ++k)
                nxt[k] = vB2[(ntn * 16 + c) * 40 + k * 4 + g];
        }
        f32x4 acc0 = {0.f, 0.f, 0.f, 0.f}, acc1 = {0.f, 0.f, 0.f, 0.f};
        #pragma unroll
        for (int k = 0; k < 10; ++k) {
            int t0 = c, t1 = 16 + c;
            bf16x8 a0  = *(const bf16x8*)(ab + ((t0 * 640 + k * 64 + g * 16) ^ ((t0 & 7) << 4)));
            bf16x8 a1f = *(const bf16x8*)(ab + ((t1 * 640 + k * 64 + g * 16) ^ ((t1 & 7) << 4)));
            acc0 = __builtin_amdgcn_mfma_f32_16x16x32_bf16(a0,  cur[k], acc0, 0, 0, 0);
            acc1 = __builtin_amdgcn_mfma_f32_16x16x32_bf16(a1f, cur[k], acc1, 0, 0, 0);
        }
        // epilogue: cosine over t for this lane's d column
        int d = nt * 16 + c;
        const float* ed = ei + d * TT;
        float dot = 0.f, cn2 = 0.f, en2 = 0.f;
        #pragma unroll
        for (int r = 0; r < 4; ++r) {
            int t0 = g * 4 + r;
            float ev = ed[t0];
            dot = fmaf(acc0[r], ev, dot);
            cn2 = fmaf(acc0[r], acc0[r], cn2);
            en2 = fmaf(ev, ev, en2);
            int t1 = 16 + g * 4 + r;
            float ev1 = (t1 < TT) ? ed[t1] : 0.f;
            dot = fmaf(acc1[r], ev1, dot);
            cn2 = fmaf(acc1[r], acc1[r], cn2);
            en2 = fmaf(ev1, ev1, en2);
        }
        dot += __shfl_xor(dot, 16, 64); cn2 += __shfl_xor(cn2, 16, 64); en2 += __shfl_xor(en2, 16, 64);
        dot += __shfl_xor(dot, 32, 64); cn2 += __shfl_xor(cn2, 32, 64); en2 += __shfl_xor(en2, 32, 64);
        float R = dot / fmaxf(sqrtf(cn2) * sqrtf(en2), 1e-8f);
        float y = 5.0f * R;
        if (y > mrun) { srun = srun * __expf(mrun - y) + 1.f; mrun = y; }
        else          { srun += __expf(y - mrun); }
    }

    // LSE: wave butterfly (each d duplicated 4x within a wave), then cross-wave
    #pragma unroll
    for (int mk = 1; mk <= 32; mk <<= 1) {
        float mo = __shfl_xor(mrun, mk, 64);
        float so = __shfl_xor(srun, mk, 64);
        float mn = fmaxf(mrun, mo);
        srun = srun * __expf(mrun - mn) + so * __expf(mo - mn);
        mrun = mn;
    }
    // reuse alpha LDS for the 8-float cross-wave scratch (alpha no longer needed)
    float* redm = (float*)alpha;       // [4]
    float* reds = (float*)alpha + 4;   // [4]
    __syncthreads();                   // all waves done reading alpha
    if (lane == 0) { redm[wave] = mrun; reds[wave] = srun; }
    __syncthreads();
    if (tid == 0) {
        float mt = fmaxf(fmaxf(redm[0], redm[1]), fmaxf(redm[2], redm[3]));
        float st = 0.f;
        #pragma unroll
        for (int w = 0; w < 4; ++w) st += reds[w] * __expf(redm[w] - mt);
        float lse = mt + logf(st * 0.25f);   // /4 removes lane-quad duplication
        Smat[bid] = powf(lse, 0.2f);
    }
}

// out[0..63] = sum_j S[i][j]; out[64..127] = sum_i S[i][j]
__global__ void reduce_kernel(const float* __restrict__ Smat, float* __restrict__ out) {
    int k = threadIdx.x;   // 0..127
    float s = 0.f;
    if (k < 64) {
        int i = k;
        for (int j = 0; j < BB; ++j) s += Smat[j * 64 + i];
        out[i] = s;
    } else {
        int jq = k - 64;
        for (int i = 0; i < BB; ++i) s += Smat[jq * 64 + i];
        out[64 + jq] = s;
    }
}

extern "C" void kernel_launch(void* const* d_in, const int* in_sizes, int n_in,
                              void* d_out, int out_size, void* d_ws, size_t ws_size,
                              hipStream_t stream) {
    const float* e = (const float*)d_in[0];
    const float* v = (const float*)d_in[1];
    float* out = (float*)d_out;
    char* ws = (char*)d_ws;
    __hip_bfloat16* eT  = (__hip_bfloat16*)(ws + ET_OFF);
    __hip_bfloat16* vT  = (__hip_bfloat16*)(ws + VT_OFF);
    __hip_bfloat16* vbf = (__hip_bfloat16*)(ws + VBF_OFF);
    float* Smat = (float*)(ws + SMAT_OFF);

    conv_e_kernel<<<64, 256, 0, stream>>>(e, eT);
    conv_v_kernel<<<512, 256, 0, stream>>>(v, vT, vbf);
    pair_kernel<<<BB * BB, 256, 0, stream>>>(e, eT, vT, vbf, Smat);
    reduce_kernel<<<1, 128, 0, stream>>>(Smat, out);
}

// Round 9
// 247.271 us; speedup vs baseline: 2.5193x; 1.3276x over previous
//
#include <hip/hip_runtime.h>
#include <hip/hip_bf16.h>
#include <math.h>

#define BB 64
#define DD 256
#define TT 24
#define NR 289

typedef float f32x4 __attribute__((ext_vector_type(4)));
typedef short bf16x8 __attribute__((ext_vector_type(8)));

// ws layout (bytes)
#define ET_OFF   0ul                     // eT  [64][32][256] bf16 (t>=24 zero)   1,048,576
#define VT_OFF   1048576ul               // vT  [64][304][256] bf16 (n>=289 zero) 9,961,472
#define VBF_OFF  11010048ul              // vbf [64][256][320] bf16 (n>=289 zero) 10,485,760
#define SMAT_OFF 21495808ul              // Smat [4096] f32

// ---- convert e -> eT[i][t][d] bf16, rows t>=24 zeroed
__global__ void conv_e_kernel(const float* __restrict__ e, __hip_bfloat16* __restrict__ eT) {
    int i = blockIdx.x, d = threadIdx.x;
    const float* src = e + ((size_t)i * DD + d) * TT;
    __hip_bfloat16* dst = eT + (size_t)i * 32 * DD + d;
    #pragma unroll
    for (int t = 0; t < 32; ++t) {
        float vv = (t < TT) ? src[t] : 0.f;
        dst[(size_t)t * DD] = __float2bfloat16(vv);
    }
}

// ---- convert v -> vT[j][n][d] and vbf[j][d][n] (both bf16, padded with zeros)
__global__ __launch_bounds__(256) void conv_v_kernel(const float* __restrict__ v,
                                                     __hip_bfloat16* __restrict__ vT,
                                                     __hip_bfloat16* __restrict__ vbf) {
    __shared__ float ld[32][305];   // pitch 305: coprime with 32 -> conflict-free col reads
    int j = blockIdx.x >> 3;
    int dbase = (blockIdx.x & 7) * 32;
    int tid = threadIdx.x;
    const float* vj = v + (size_t)j * DD * NR;
    for (int r = 0; r < 32; ++r) {
        const float* row = vj + (size_t)(dbase + r) * NR;
        ld[r][tid] = row[tid];
        if (tid < 48) {
            int n = 256 + tid;
            ld[r][n] = (n < NR) ? row[n] : 0.f;
        }
    }
    __syncthreads();
    { // vT[j][n][dbase+d], coalesced 32-lane writes
        int d = tid & 31, ng = tid >> 5;
        __hip_bfloat16* base = vT + (size_t)j * 304 * DD + dbase + d;
        for (int n = ng; n < 304; n += 8)
            base[(size_t)n * DD] = __float2bfloat16(ld[d][n]);
    }
    { // vbf[j][dbase+r][n], coalesced
        __hip_bfloat16* base = vbf + ((size_t)j * DD + dbase) * 320;
        for (int idx = tid; idx < 32 * 320; idx += 256) {
            int r = idx / 320, n = idx - r * 320;
            float vv = (n < NR) ? ld[r][n] : 0.f;
            base[(size_t)r * 320 + n] = __float2bfloat16(vv);
        }
    }
}

// ---- one block (256 thr) per (i,j) pair; Smat[j*64+i] = S[i][j]
// EXACT round-4 body (proven: 60 VGPR, spill-free, 226 us) + two zero-register
// deltas: XCD-aware bid swizzle (L2-resident v[j]) and pad-lite zeroing.
// Register ledger (unified VGPR+AGPR ~100-125): ONLY cap 128 is spill-free.
__global__ __launch_bounds__(256, 4) void pair_kernel(const float* __restrict__ e,
                                                      const __hip_bfloat16* __restrict__ eT,
                                                      const __hip_bfloat16* __restrict__ vT,
                                                      const __hip_bfloat16* __restrict__ vbf,
                                                      float* __restrict__ Smat) {
    __shared__ __align__(16) __hip_bfloat16 alpha[32 * 320];   // 20480 B, XOR-swizzled rows

    const int tid = threadIdx.x;
    const int wave = tid >> 6, lane = tid & 63;
    const int c = lane & 15, g = lane >> 4;
    // XCD swizzle (T1): bijective (4096 = 8*512); each XCD serves 8 j's (2.6 MB < 4 MB L2)
    const int bid = (blockIdx.x & 7) * 512 + (blockIdx.x >> 3);
    const int i = bid & 63, j = bid >> 6;

    char* ab = (char*)alpha;

    // pad-lite zeroing: only the regions GEMM2 reads that GEMM1 never writes.
    //  rows 24..31 full (A rows t>=24 must be 0), cols 304..319 all rows (swizzled).
    {
        uint32_t* rz = (uint32_t*)(ab + 24 * 640);   // 8 rows * 640 B
        #pragma unroll
        for (int q = 0; q < 5; ++q) rz[tid + q * 256] = 0u;
        int t = tid >> 3, n0 = 304 + 2 * (tid & 7);  // 32 rows x 16 cols, swizzled
        int boff = (t * 640 + 2 * n0) ^ ((t & 7) << 4);
        *(uint32_t*)(ab + boff) = 0u;
    }
    // no barrier: pad region is only read in GEMM2, two barriers away; disjoint
    // from every earlier write/read.

    // ================= GEMM1: s[t][n] = sum_d eT[i][t][d] * v[j][d][n] ==========
    const bf16x8* eA = (const bf16x8*)(eT + (size_t)i * 32 * DD);
    bf16x8 a1[2][8];
    #pragma unroll
    for (int m = 0; m < 2; ++m)
        #pragma unroll
        for (int k = 0; k < 8; ++k)
            a1[m][k] = eA[(m * 16 + c) * 32 + k * 4 + g];

    const bf16x8* vB = (const bf16x8*)(vT + (size_t)j * 304 * DD);
    for (int nt = wave; nt < 19; nt += 4) {
        bf16x8 b1[8];
        #pragma unroll
        for (int k = 0; k < 8; ++k)
            b1[k] = vB[(nt * 16 + c) * 32 + k * 4 + g];
        f32x4 acc0 = {0.f, 0.f, 0.f, 0.f}, acc1 = {0.f, 0.f, 0.f, 0.f};
        #pragma unroll
        for (int k = 0; k < 8; ++k) {
            acc0 = __builtin_amdgcn_mfma_f32_16x16x32_bf16(a1[0][k], b1[k], acc0, 0, 0, 0);
            acc1 = __builtin_amdgcn_mfma_f32_16x16x32_bf16(a1[1][k], b1[k], acc1, 0, 0, 0);
        }
        // store scores as bf16 into the swizzled alpha buffer
        #pragma unroll
        for (int r = 0; r < 4; ++r) {
            int t0 = g * 4 + r;
            int b0 = ((t0 * 320 + nt * 16 + c) * 2) ^ ((t0 & 7) << 4);
            *(__hip_bfloat16*)(ab + b0) = __float2bfloat16(acc0[r]);
            int t1 = 16 + g * 4 + r;
            if (t1 < TT) {
                int b1o = ((t1 * 320 + nt * 16 + c) * 2) ^ ((t1 & 7) << 4);
                *(__hip_bfloat16*)(ab + b1o) = __float2bfloat16(acc1[r]);
            }
        }
    }
    __syncthreads();

    // ============ softmax over n, in place on bf16 rows (wave owns 6 t-rows) ====
    #pragma unroll
    for (int tt = 0; tt < 6; ++tt) {
        int t = wave * 6 + tt;
        int base = t * 640, sw = (t & 7) << 4;
        float vls[5];
        #pragma unroll
        for (int k5 = 0; k5 < 5; ++k5) {
            int n = k5 * 64 + lane;
            vls[k5] = (n < NR)
                ? __bfloat162float(*(const __hip_bfloat16*)(ab + ((base + 2 * n) ^ sw)))
                : -INFINITY;
        }
        float m = vls[0];
        #pragma unroll
        for (int k5 = 1; k5 < 5; ++k5) m = fmaxf(m, vls[k5]);
        #pragma unroll
        for (int mk = 32; mk >= 1; mk >>= 1) m = fmaxf(m, __shfl_xor(m, mk, 64));
        float sum = 0.f;
        #pragma unroll
        for (int k5 = 0; k5 < 5; ++k5) { vls[k5] = __expf(vls[k5] - m); sum += vls[k5]; }
        #pragma unroll
        for (int mk = 32; mk >= 1; mk >>= 1) sum += __shfl_xor(sum, mk, 64);
        float inv = 1.f / sum;
        #pragma unroll
        for (int k5 = 0; k5 < 5; ++k5) {
            int n = k5 * 64 + lane;
            if (n < NR)
                *(__hip_bfloat16*)(ab + ((base + 2 * n) ^ sw)) = __float2bfloat16(vls[k5] * inv);
        }
    }
    __syncthreads();

    // ====== softmax over t of G1*s_norm, in place per column (thread <-> n) =====
    for (int p = 0; p < 2; ++p) {
        int n = p * 256 + tid;
        if (n < NR) {
            float vals[TT];
            #pragma unroll
            for (int t = 0; t < TT; ++t)
                vals[t] = __bfloat162float(
                    *(const __hip_bfloat16*)(ab + ((t * 640 + 2 * n) ^ ((t & 7) << 4))));
            float m = vals[0];
            #pragma unroll
            for (int t = 1; t < TT; ++t) m = fmaxf(m, vals[t]);
            m *= 4.0f;
            float sum = 0.f;
            #pragma unroll
            for (int t = 0; t < TT; ++t) { vals[t] = __expf(4.0f * vals[t] - m); sum += vals[t]; }
            float inv = 1.f / sum;
            #pragma unroll
            for (int t = 0; t < TT; ++t)
                *(__hip_bfloat16*)(ab + ((t * 640 + 2 * n) ^ ((t & 7) << 4))) =
                    __float2bfloat16(vals[t] * inv);
        }
    }
    __syncthreads();

    // ====== GEMM2: c[t][d] = sum_n alpha[t][n]*v[d][n]; fused epilogue ==========
    bf16x8 a2[2][10];
    {
        #pragma unroll
        for (int m = 0; m < 2; ++m) {
            int t = m * 16 + c;
            int sw = (t & 7) << 4;
            #pragma unroll
            for (int k = 0; k < 10; ++k) {
                int boff = (t * 640 + k * 64 + g * 16) ^ sw;
                a2[m][k] = *(const bf16x8*)(ab + boff);
            }
        }
    }
    const bf16x8* vB2 = (const bf16x8*)(vbf + (size_t)j * DD * 320);
    const float* ei = e + (size_t)i * DD * TT;

    float mrun = -INFINITY, srun = 0.f;
    for (int q = 0; q < 4; ++q) {
        int nt = wave + q * 4;   // d-tile
        bf16x8 b2[10];
        #pragma unroll
        for (int k = 0; k < 10; ++k)
            b2[k] = vB2[(nt * 16 + c) * 40 + k * 4 + g];
        f32x4 acc0 = {0.f, 0.f, 0.f, 0.f}, acc1 = {0.f, 0.f, 0.f, 0.f};
        #pragma unroll
        for (int k = 0; k < 10; ++k) {
            acc0 = __builtin_amdgcn_mfma_f32_16x16x32_bf16(a2[0][k], b2[k], acc0, 0, 0, 0);
            acc1 = __builtin_amdgcn_mfma_f32_16x16x32_bf16(a2[1][k], b2[k], acc1, 0, 0, 0);
        }
        // epilogue: cosine over t for this lane's d column
        int d = nt * 16 + c;
        const float* ed = ei + d * TT;
        float dot = 0.f, cn2 = 0.f, en2 = 0.f;
        #pragma unroll
        for (int r = 0; r < 4; ++r) {
            int t0 = g * 4 + r;
            float ev = ed[t0];
            dot = fmaf(acc0[r], ev, dot);
            cn2 = fmaf(acc0[r], acc0[r], cn2);
            en2 = fmaf(ev, ev, en2);
            int t1 = 16 + g * 4 + r;
            float ev1 = (t1 < TT) ? ed[t1] : 0.f;
            dot = fmaf(acc1[r], ev1, dot);
            cn2 = fmaf(acc1[r], acc1[r], cn2);
            en2 = fmaf(ev1, ev1, en2);
        }
        dot += __shfl_xor(dot, 16, 64); cn2 += __shfl_xor(cn2, 16, 64); en2 += __shfl_xor(en2, 16, 64);
        dot += __shfl_xor(dot, 32, 64); cn2 += __shfl_xor(cn2, 32, 64); en2 += __shfl_xor(en2, 32, 64);
        float R = dot / fmaxf(sqrtf(cn2) * sqrtf(en2), 1e-8f);
        float y = 5.0f * R;
        if (y > mrun) { srun = srun * __expf(mrun - y) + 1.f; mrun = y; }
        else          { srun += __expf(y - mrun); }
    }

    // LSE: wave butterfly (each d duplicated 4x within a wave), then cross-wave
    #pragma unroll
    for (int mk = 1; mk <= 32; mk <<= 1) {
        float mo = __shfl_xor(mrun, mk, 64);
        float so = __shfl_xor(srun, mk, 64);
        float mn = fmaxf(mrun, mo);
        srun = srun * __expf(mrun - mn) + so * __expf(mo - mn);
        mrun = mn;
    }
    // reuse alpha LDS for the 8-float cross-wave scratch (alpha no longer needed)
    float* redm = (float*)alpha;       // [4]
    float* reds = (float*)alpha + 4;   // [4]
    __syncthreads();                   // all waves done reading a2
    if (lane == 0) { redm[wave] = mrun; reds[wave] = srun; }
    __syncthreads();
    if (tid == 0) {
        float mt = fmaxf(fmaxf(redm[0], redm[1]), fmaxf(redm[2], redm[3]));
        float st = 0.f;
        #pragma unroll
        for (int w = 0; w < 4; ++w) st += reds[w] * __expf(redm[w] - mt);
        float lse = mt + logf(st * 0.25f);   // /4 removes lane-quad duplication
        Smat[bid] = powf(lse, 0.2f);
    }
}

// out[0..63] = sum_j S[i][j]; out[64..127] = sum_i S[i][j]
__global__ void reduce_kernel(const float* __restrict__ Smat, float* __restrict__ out) {
    int k = threadIdx.x;   // 0..127
    float s = 0.f;
    if (k < 64) {
        int i = k;
        for (int j = 0; j < BB; ++j) s += Smat[j * 64 + i];
        out[i] = s;
    } else {
        int jq = k - 64;
        for (int i = 0; i < BB; ++i) s += Smat[jq * 64 + i];
        out[64 + jq] = s;
    }
}

extern "C" void kernel_launch(void* const* d_in, const int* in_sizes, int n_in,
                              void* d_out, int out_size, void* d_ws, size_t ws_size,
                              hipStream_t stream) {
    const float* e = (const float*)d_in[0];
    const float* v = (const float*)d_in[1];
    float* out = (float*)d_out;
    char* ws = (char*)d_ws;
    __hip_bfloat16* eT  = (__hip_bfloat16*)(ws + ET_OFF);
    __hip_bfloat16* vT  = (__hip_bfloat16*)(ws + VT_OFF);
    __hip_bfloat16* vbf = (__hip_bfloat16*)(ws + VBF_OFF);
    float* Smat = (float*)(ws + SMAT_OFF);

    conv_e_kernel<<<64, 256, 0, stream>>>(e, eT);
    conv_v_kernel<<<512, 256, 0, stream>>>(v, vT, vbf);
    pair_kernel<<<BB * BB, 256, 0, stream>>>(e, eT, vT, vbf, Smat);
    reduce_kernel<<<1, 128, 0, stream>>>(Smat, out);
}